// Round 4
// baseline (352.449 us; speedup 1.0000x reference)
//
#include <hip/hip_runtime.h>
#include <stdint.h>

// SelfAttention: bf16x3 MFMA GEMMs + DMA-staged MFMA flash attention.
// R13->R14: counted-vmcnt prefetch with a FULL compute-phase of lead.
// (1) qkv: all 4 stages of tile t+1 issued at phase 0 of tile t, vmcnt(8)
//     -> tile t's loads get a whole K-tile of MFMA to hide HBM latency
//     (previously stage(3,t) was issued one phase before its drain).
// (2) flash: rewritten as 32 iters x one 24KB tile, true double-buffer:
//     prefetch t+1 (6 loads/wave), vmcnt(6), RAW s_barrier (not
//     __syncthreads, which drains vmcnt to 0 and killed the pipeline).

#define BATCH 2
#define SEQ 2048
#define DM 1024
#define NH 16
#define HD 64
#define M_TOT 4096
// 1/sqrt(HD) * log2(e): scores come out in base-2 domain
#define QSCALE 0.18033688011112042f

typedef __bf16 bf16x8 __attribute__((ext_vector_type(8)));
typedef __bf16 bf16x4 __attribute__((ext_vector_type(4)));
typedef float  f32x4  __attribute__((ext_vector_type(4)));

__device__ __forceinline__ void gld_lds16(const void* g, void* l) {
    __builtin_amdgcn_global_load_lds(
        (const __attribute__((address_space(1))) uint32_t*)g,
        (__attribute__((address_space(3))) uint32_t*)l, 16, 0, 0);
}

// ---------------- prep: fp32 -> bf16 hi/lo splits (x, Wqkv^T, Wout^T) -------
__launch_bounds__(256)
__global__ void prep_kernel(const float* __restrict__ x,
                            const float* __restrict__ Wqkv,
                            const float* __restrict__ Wout,
                            __bf16* __restrict__ xs,
                            __bf16* __restrict__ wqt,
                            __bf16* __restrict__ wot)
{
    __shared__ float T[64][69];
    const int tid = threadIdx.x;
    const int blk = blockIdx.x;

    if (blk < 4096) {
        const int i  = blk * 256 + tid;
        const int m  = i >> 8;
        const int c4 = (i & 255) * 4;
        float4 v = *reinterpret_cast<const float4*>(&x[(size_t)m * DM + c4]);
        float a[4] = {v.x, v.y, v.z, v.w};
        bf16x4 hi, lo;
        #pragma unroll
        for (int j = 0; j < 4; ++j) {
            __bf16 h = (__bf16)a[j];
            hi[j] = h;
            lo[j] = (__bf16)(a[j] - (float)h);
        }
        *reinterpret_cast<bf16x4*>(&xs[(size_t)m * (2*DM) + c4]) = hi;
        *reinterpret_cast<bf16x4*>(&xs[(size_t)m * (2*DM) + DM + c4]) = lo;
        return;
    }

    const int bb = (blk < 4864) ? blk - 4096 : blk - 4864;
    const float* W = (blk < 4864) ? Wqkv : Wout;
    __bf16* Wt     = (blk < 4864) ? wqt  : wot;
    const int N    = (blk < 4864) ? 3 * DM : DM;
    const int k0 = (bb & 15) * 64, n0 = (bb >> 4) * 64;

    {
        const int kr = tid >> 4, c4 = (tid & 15) * 4;
        #pragma unroll
        for (int i = 0; i < 4; ++i) {
            float4 v = *reinterpret_cast<const float4*>(
                &W[(size_t)(k0 + kr + 16 * i) * N + n0 + c4]);
            *reinterpret_cast<float4*>(&T[kr + 16 * i][c4]) = v;
        }
    }
    __syncthreads();
    {
        const int n = tid >> 2, kc = (tid & 3) * 16;
        __bf16 hi[16], lo[16];
        #pragma unroll
        for (int j = 0; j < 16; ++j) {
            float v = T[kc + j][n];
            __bf16 h = (__bf16)v;
            hi[j] = h;
            lo[j] = (__bf16)(v - (float)h);
        }
        const size_t ro = (size_t)(n0 + n) * (2*DM) + k0 + kc;
        *reinterpret_cast<bf16x8*>(&Wt[ro])          = *reinterpret_cast<bf16x8*>(&hi[0]);
        *reinterpret_cast<bf16x8*>(&Wt[ro + 8])      = *reinterpret_cast<bf16x8*>(&hi[8]);
        *reinterpret_cast<bf16x8*>(&Wt[ro + DM])     = *reinterpret_cast<bf16x8*>(&lo[0]);
        *reinterpret_cast<bf16x8*>(&Wt[ro + DM + 8]) = *reinterpret_cast<bf16x8*>(&lo[8]);
    }
}

// ---------------- QKV GEMM: 256x256 4-phase, BK=64, virtual-K'=3072 ---------
// 512 threads = 8 waves (2M x 4N). Per wave 128x64 output = acc[8][4].
// LDS: 2 x (A 256x64 + B 256x64) bf16 = 128KB, xor-8 swizzled 64-wide rows.
// All 4 stages of tile t+1 issue at phase 0 of tile t; vmcnt(8) keeps them
// in flight across the whole K-tile. Phases 1-3 are pure ds_read+MFMA.
__launch_bounds__(512, 2)
__global__ void gemm_qkv_kernel(const __bf16* __restrict__ A,
                                const __bf16* __restrict__ Bt,
                                const float* __restrict__ bias,
                                __bf16* __restrict__ qs,
                                __bf16* __restrict__ khi_g,
                                __bf16* __restrict__ klo_g,
                                __bf16* __restrict__ vt_g)
{
    __shared__ __align__(16) __bf16 pool[65536];   // 128 KB

    const int tid  = threadIdx.x;
    const int w    = tid >> 6;            // 0..7
    const int lane = tid & 63;
    const int n16  = lane & 15;
    const int quad = lane >> 4;

    // bijective XCD swizzle over 192 blocks (192 % 8 == 0)
    const int wg = (blockIdx.x & 7) * 24 + (blockIdx.x >> 3);
    const int bm = (wg & 15) * 256;       // 16 M-tiles
    const int bn = (wg >> 4) * 256;       // 12 N-tiles

    const int wm = (w >> 2) * 128;        // wave M offset (2)
    const int wn = (w & 3) * 64;          // wave N offset (4)

    // staging: thread stages chunks ci0=tid, ci1=512+tid of each 128x64 half.
    // LDS is linear in chunk order; global col-chunk is xor-swizzled so that
    // swizzled ds_reads see the right data (inverse == forward, involution).
    const int r0 = tid >> 3;                       // 0..63 (slot1 = r0+64)
    const int c0 = ((tid & 7) ^ (r0 & 7));         // col chunk (both slots)

    auto stage = [&](int p, int kcol, int nbuf) {
        __bf16* dst = pool + nbuf * 32768 + p * 8192;
        const __bf16* gsrc = (p < 2)
            ? A  + (size_t)(bm + p * 128) * (2*DM) + kcol
            : Bt + (size_t)(bn + (p - 2) * 128) * (2*DM) + kcol;
        gld_lds16(gsrc + (size_t)r0 * (2*DM) + c0 * 8,        dst + (size_t)tid * 8);
        gld_lds16(gsrc + (size_t)(r0 + 64) * (2*DM) + c0 * 8, dst + (size_t)(512 + tid) * 8);
    };

    // fragment read addressing (xor-8 swizzle, conflict-even)
    const int rowA = (wm + n16) * 64;
    const int rowB = (wn + n16) * 64;
    const int sx0 = ((quad)     ^ (n16 & 7)) << 3;   // k-half 0
    const int sx1 = ((4 + quad) ^ (n16 & 7)) << 3;   // k-half 1

    f32x4 acc[8][4] = {};
    bf16x8 af[4][2], bf0[2][2], bf1[2][2];

    // prologue: stage tile 0 fully into buf 0
    stage(0, 0, 0); stage(1, 0, 0); stage(2, 0, 0); stage(3, 0, 0);

    #pragma unroll 2
    for (int t = 0; t < 48; ++t) {
        const int buf = t & 1;
        const __bf16* bufA = pool + buf * 32768;
        const __bf16* bufB = bufA + 16384;
        const int nbuf = buf ^ 1;
        const bool pre = (t < 47);
        const int tt = t + 1;
        const int a_k = (tt < 16) ? tt * 64 : tt * 64 - DM;       // [xh|xh|xl]
        const int b_k = (tt < 32) ? tt * 64 : tt * 64 - 2 * DM;   // [wh|wl|wh]

        // ---- phase 0: stage ALL of tile t+1, then quadrant (M0,N0) ----
        // Writes to nbuf are safe: nbuf == buf(t-1), and every wave's
        // ds_reads of buf(t-1) completed (own lgkmcnt(0)) before it passed
        // the phase-3 barrier of t-1.
        if (pre) {
            stage(0, a_k, nbuf);
            stage(1, a_k, nbuf);
            stage(2, b_k, nbuf);
            stage(3, b_k, nbuf);
            asm volatile("s_waitcnt vmcnt(8)" ::: "memory");
        } else {
            asm volatile("s_waitcnt vmcnt(0)" ::: "memory");
        }
        __builtin_amdgcn_s_barrier();
        __builtin_amdgcn_sched_barrier(0);
        #pragma unroll
        for (int i = 0; i < 4; ++i) {
            af[i][0] = *reinterpret_cast<const bf16x8*>(bufA + rowA + i * 1024 + sx0);
            af[i][1] = *reinterpret_cast<const bf16x8*>(bufA + rowA + i * 1024 + sx1);
        }
        #pragma unroll
        for (int j = 0; j < 2; ++j) {
            bf0[j][0] = *reinterpret_cast<const bf16x8*>(bufB + rowB + j * 1024 + sx0);
            bf0[j][1] = *reinterpret_cast<const bf16x8*>(bufB + rowB + j * 1024 + sx1);
        }
        asm volatile("s_waitcnt lgkmcnt(0)" ::: "memory");
        __builtin_amdgcn_sched_barrier(0);
        __builtin_amdgcn_s_setprio(1);
        #pragma unroll
        for (int i = 0; i < 4; ++i)
            #pragma unroll
            for (int j = 0; j < 2; ++j) {
                acc[i][j] = __builtin_amdgcn_mfma_f32_16x16x32_bf16(af[i][0], bf0[j][0], acc[i][j], 0, 0, 0);
                acc[i][j] = __builtin_amdgcn_mfma_f32_16x16x32_bf16(af[i][1], bf0[j][1], acc[i][j], 0, 0, 0);
            }
        __builtin_amdgcn_s_setprio(0);

        // ---- phase 1: quadrant (M0,N1) ----
        #pragma unroll
        for (int j = 0; j < 2; ++j) {
            bf1[j][0] = *reinterpret_cast<const bf16x8*>(bufB + rowB + (2 + j) * 1024 + sx0);
            bf1[j][1] = *reinterpret_cast<const bf16x8*>(bufB + rowB + (2 + j) * 1024 + sx1);
        }
        __builtin_amdgcn_s_barrier();
        __builtin_amdgcn_sched_barrier(0);
        asm volatile("s_waitcnt lgkmcnt(0)" ::: "memory");
        __builtin_amdgcn_sched_barrier(0);
        __builtin_amdgcn_s_setprio(1);
        #pragma unroll
        for (int i = 0; i < 4; ++i)
            #pragma unroll
            for (int j = 0; j < 2; ++j) {
                acc[i][2 + j] = __builtin_amdgcn_mfma_f32_16x16x32_bf16(af[i][0], bf1[j][0], acc[i][2 + j], 0, 0, 0);
                acc[i][2 + j] = __builtin_amdgcn_mfma_f32_16x16x32_bf16(af[i][1], bf1[j][1], acc[i][2 + j], 0, 0, 0);
            }
        __builtin_amdgcn_s_setprio(0);

        // ---- phase 2: quadrant (M1,N0) ----
        #pragma unroll
        for (int i = 0; i < 4; ++i) {
            af[i][0] = *reinterpret_cast<const bf16x8*>(bufA + rowA + (4 + i) * 1024 + sx0);
            af[i][1] = *reinterpret_cast<const bf16x8*>(bufA + rowA + (4 + i) * 1024 + sx1);
        }
        __builtin_amdgcn_s_barrier();
        __builtin_amdgcn_sched_barrier(0);
        asm volatile("s_waitcnt lgkmcnt(0)" ::: "memory");
        __builtin_amdgcn_sched_barrier(0);
        __builtin_amdgcn_s_setprio(1);
        #pragma unroll
        for (int i = 0; i < 4; ++i)
            #pragma unroll
            for (int j = 0; j < 2; ++j) {
                acc[4 + i][j] = __builtin_amdgcn_mfma_f32_16x16x32_bf16(af[i][0], bf0[j][0], acc[4 + i][j], 0, 0, 0);
                acc[4 + i][j] = __builtin_amdgcn_mfma_f32_16x16x32_bf16(af[i][1], bf0[j][1], acc[4 + i][j], 0, 0, 0);
            }
        __builtin_amdgcn_s_setprio(0);

        // ---- phase 3: quadrant (M1,N1) ----
        __builtin_amdgcn_s_barrier();
        __builtin_amdgcn_sched_barrier(0);
        __builtin_amdgcn_s_setprio(1);
        #pragma unroll
        for (int i = 0; i < 4; ++i)
            #pragma unroll
            for (int j = 0; j < 2; ++j) {
                acc[4 + i][2 + j] = __builtin_amdgcn_mfma_f32_16x16x32_bf16(af[i][0], bf1[j][0], acc[4 + i][2 + j], 0, 0, 0);
                acc[4 + i][2 + j] = __builtin_amdgcn_mfma_f32_16x16x32_bf16(af[i][1], bf1[j][1], acc[4 + i][2 + j], 0, 0, 0);
            }
        __builtin_amdgcn_s_setprio(0);
    }

    // Fenced barrier before reusing pool as epilogue scratch (race fix, R13).
    __syncthreads();

    // ---- epilogue: wave-private LDS transpose, coalesced b128 stores ----
    const int colb = bn + wn;
    const int part = colb >> 10;              // 0:Q 1:K 2:V (block-uniform)
    const int hh   = (colb & 1023) >> 6;

    float bv[4];
    #pragma unroll
    for (int j = 0; j < 4; ++j) bv[j] = bias[colb + j * 16 + n16];

    __bf16* scrH = pool + w * 4608;
    __bf16* scrL = scrH + 2304;
    const int lr = lane & 31, hc = lane >> 5;

    #pragma unroll
    for (int mi = 0; mi < 2; ++mi) {
        const int brow = bm + wm + mi * 64;
        const int b    = brow >> 11;
        const int s0   = brow & 2047;
        const int bh   = b * NH + hh;
        const int kt   = s0 >> 6;
        const size_t tb = ((size_t)bh * 32 + kt) * 4096;

        #pragma unroll
        for (int p = 0; p < 2; ++p) {
            if (part == 2) {
                #pragma unroll
                for (int jj = 0; jj < 2; ++jj) {
                    const int j = 2 * p + jj;
                    #pragma unroll
                    for (int i = 0; i < 4; ++i) {
                        bf16x4 v4;
                        #pragma unroll
                        for (int r = 0; r < 4; ++r)
                            v4[r] = (__bf16)(acc[4 * mi + i][j][r] + bv[j]);
                        *reinterpret_cast<bf16x4*>(
                            &scrH[(jj * 16 + n16) * 72 + i * 16 + quad * 4]) = v4;
                    }
                }
            } else {
                #pragma unroll
                for (int ii = 0; ii < 2; ++ii) {
                    const int i = 2 * p + ii;
                    #pragma unroll
                    for (int j = 0; j < 4; ++j) {
                        #pragma unroll
                        for (int r = 0; r < 4; ++r) {
                            float val = acc[4 * mi + i][j][r] + bv[j];
                            if (part == 0) val *= QSCALE;   // 1/sqrt(HD)*log2e
                            __bf16 h = (__bf16)val;
                            const int so = (ii * 16 + quad * 4 + r) * 72 + j * 16 + n16;
                            scrH[so] = h;
                            scrL[so] = (__bf16)(val - (float)h);
                        }
                    }
                }
            }
            __syncthreads();

            if (part == 0) {
                const size_t qbase = ((size_t)bh * SEQ + s0 + 32 * p + lr) * 128;
                #pragma unroll
                for (int t = 0; t < 4; ++t) {
                    const int ch = hc * 4 + t;
                    *reinterpret_cast<bf16x8*>(&qs[qbase + ch * 8]) =
                        *reinterpret_cast<const bf16x8*>(&scrH[lr * 72 + ch * 8]);
                    *reinterpret_cast<bf16x8*>(&qs[qbase + 64 + ch * 8]) =
                        *reinterpret_cast<const bf16x8*>(&scrL[lr * 72 + ch * 8]);
                }
            } else if (part == 1) {
                const int kr = 32 * p + lr;
                #pragma unroll
                for (int t = 0; t < 4; ++t) {
                    const int ch = hc * 4 + t;
                    const int src = (ch ^ (lr & 7)) * 8;
                    *reinterpret_cast<bf16x8*>(&khi_g[tb + kr * 64 + ch * 8]) =
                        *reinterpret_cast<const bf16x8*>(&scrH[lr * 72 + src]);
                    *reinterpret_cast<bf16x8*>(&klo_g[tb + kr * 64 + ch * 8]) =
                        *reinterpret_cast<const bf16x8*>(&scrL[lr * 72 + src]);
                }
            } else {
                const int d = 32 * p + lr;
                #pragma unroll
                for (int t = 0; t < 4; ++t) {
                    const int ch = hc * 4 + t;
                    const int src = (ch ^ (lr & 7)) * 8;
                    *reinterpret_cast<bf16x8*>(&vt_g[tb + d * 64 + ch * 8]) =
                        *reinterpret_cast<const bf16x8*>(&scrH[lr * 72 + src]);
                }
            }
            __syncthreads();
        }
    }
}

// ---------------- out-proj GEMM (bf16x3, 128x64 tile, fused-K loop) ----------
__launch_bounds__(256)
__global__ void gemm_out_kernel(const __bf16* __restrict__ A,
                                const __bf16* __restrict__ Bt,
                                const float* __restrict__ bias,
                                float* __restrict__ out)
{
    __shared__ __align__(16) __bf16 AsH[128 * 32];
    __shared__ __align__(16) __bf16 AsL[128 * 32];
    __shared__ __align__(16) __bf16 BsH[64 * 32];
    __shared__ __align__(16) __bf16 BsL[64 * 32];

    const int tid  = threadIdx.x;
    const int w    = tid >> 6;
    const int lane = tid & 63;
    const int n16  = lane & 15;
    const int quad = lane >> 4;
    const int bm = blockIdx.x * 128, bn = blockIdx.y * 64;
    const int wm = (w & 1) * 64,     wn = (w >> 1) * 32;

    const int srow = tid >> 2, sc = (tid & 3) * 8;
    const __bf16* Ar = A  + (size_t)(bm + srow) * (2*DM) + sc;
    const __bf16* Br = Bt + (size_t)(bn + srow) * (2*DM) + sc;   // rows 0..63

    f32x4 acc[4][2] = {};

    for (int k0 = 0; k0 < DM; k0 += 32) {
        __syncthreads();
        gld_lds16(Ar + k0,                         &AsH[(size_t)tid * 8]);
        gld_lds16(Ar + k0 + (size_t)64*2*DM,       &AsH[(size_t)(256 + tid) * 8]);
        gld_lds16(Ar + DM + k0,                    &AsL[(size_t)tid * 8]);
        gld_lds16(Ar + DM + k0 + (size_t)64*2*DM,  &AsL[(size_t)(256 + tid) * 8]);
        gld_lds16(Br + k0,                         &BsH[(size_t)tid * 8]);
        gld_lds16(Br + DM + k0,                    &BsL[(size_t)tid * 8]);
        __syncthreads();

        bf16x8 afh[4], afl[4], bfh[2], bfl[2];
        #pragma unroll
        for (int i = 0; i < 4; ++i) {
            const int ro = (wm + i*16 + n16) * 32 + quad * 8;
            afh[i] = *reinterpret_cast<const bf16x8*>(&AsH[ro]);
            afl[i] = *reinterpret_cast<const bf16x8*>(&AsL[ro]);
        }
        #pragma unroll
        for (int j = 0; j < 2; ++j) {
            const int ro = (wn + j*16 + n16) * 32 + quad * 8;
            bfh[j] = *reinterpret_cast<const bf16x8*>(&BsH[ro]);
            bfl[j] = *reinterpret_cast<const bf16x8*>(&BsL[ro]);
        }
        #pragma unroll
        for (int i = 0; i < 4; ++i)
            #pragma unroll
            for (int j = 0; j < 2; ++j) {
                acc[i][j] = __builtin_amdgcn_mfma_f32_16x16x32_bf16(afh[i], bfh[j], acc[i][j], 0, 0, 0);
                acc[i][j] = __builtin_amdgcn_mfma_f32_16x16x32_bf16(afh[i], bfl[j], acc[i][j], 0, 0, 0);
                acc[i][j] = __builtin_amdgcn_mfma_f32_16x16x32_bf16(afl[i], bfh[j], acc[i][j], 0, 0, 0);
            }
    }

    #pragma unroll
    for (int j = 0; j < 2; ++j) {
        const int col = bn + wn + j * 16 + n16;
        const float bvv = bias[col];
        #pragma unroll
        for (int i = 0; i < 4; ++i) {
            const int row0 = bm + wm + i * 16 + quad * 4;
            #pragma unroll
            for (int r = 0; r < 4; ++r)
                out[(size_t)(row0 + r) * DM + col] = acc[i][j][r] + bvv;
        }
    }
}

// ---------------- Flash attention: 32 x 24KB tiles, true double-buffer -----
// grid 512 (XCD-swizzled), 4 waves. Wave w owns queries qt*128 + w*32 .. +31.
// Prefetch tile t+1 (6 gld_lds/wave) at top of iter t; vmcnt(6) keeps it in
// flight across the whole compute phase; raw s_barrier (no vmcnt drain).
__launch_bounds__(256, 2)
__global__ void flash_attn_v5_kernel(const __bf16* __restrict__ qs,
                                     const __bf16* __restrict__ khi_g,
                                     const __bf16* __restrict__ klo_g,
                                     const __bf16* __restrict__ vt_g,
                                     __bf16* __restrict__ ctx2)
{
    __shared__ __align__(16) __bf16 Khi[2][4096];
    __shared__ __align__(16) __bf16 Klo[2][4096];
    __shared__ __align__(16) __bf16 Vt [2][4096];
    __shared__ __align__(16) __bf16 Ps [8192];   // 128 q-rows x 64, swizzled

    const int tid  = threadIdx.x;
    const int w    = tid >> 6;            // 0..3
    const int lane = tid & 63;
    const int n16  = lane & 15;
    const int quad = lane >> 4;
    const int bid  = blockIdx.x;
    const int bh = (bid & 7) * 4 + (bid >> 7);
    const int qt = (bid >> 3) & 15;

    bf16x8 qh[2][2], ql[2][2];
    #pragma unroll
    for (int qg = 0; qg < 2; ++qg) {
        const size_t qrow =
            ((size_t)bh * SEQ + qt * 128 + w * 32 + qg * 16 + n16) * 128;
        #pragma unroll
        for (int s2 = 0; s2 < 2; ++s2) {
            qh[qg][s2] = *reinterpret_cast<const bf16x8*>(&qs[qrow + s2 * 32 + quad * 8]);
            ql[qg][s2] = *reinterpret_cast<const bf16x8*>(&qs[qrow + 64 + s2 * 32 + quad * 8]);
        }
    }

    f32x4 o[2][4] = {};
    float l_lane[2] = {};

    // staging helper: tile kt -> buffer b; 24 x 1KB chunks over 4 waves.
    auto stage_tile = [&](int kt, int b) {
        const size_t tb = ((size_t)bh * 32 + kt) * 4096;
        #pragma unroll
        for (int t = 0; t < 6; ++t) {
            const int c = w * 6 + t;             // 0..23
            const int arr = c >> 3, sub = c & 7;
            const int eo = sub * 512 + lane * 8;
            const __bf16* g = (arr == 0 ? khi_g : arr == 1 ? klo_g : vt_g) + tb + eo;
            __bf16* l = (arr == 0 ? Khi[b] : arr == 1 ? Klo[b] : Vt[b]) + eo;
            gld_lds16(g, l);
        }
    };

    // prologue: stage tile 0 into buf 0
    stage_tile(0, 0);

    #pragma unroll 2
    for (int kt = 0; kt < 32; ++kt) {
        const int cur = kt & 1;
        if (kt < 31) {
            stage_tile(kt + 1, cur ^ 1);
            asm volatile("s_waitcnt vmcnt(6)" ::: "memory");
        } else {
            asm volatile("s_waitcnt vmcnt(0)" ::: "memory");
        }
        __builtin_amdgcn_s_barrier();
        __builtin_amdgcn_sched_barrier(0);

        const __bf16* KhiB = Khi[cur];
        const __bf16* KloB = Klo[cur];
        const __bf16* VtB  = Vt[cur];

        #pragma unroll
        for (int kg = 0; kg < 4; ++kg) {
            const int r = kg * 16 + n16;
            const int o0 = r * 64 + ((quad ^ (r & 7)) << 3);
            const int o1 = r * 64 + (((4 + quad) ^ (r & 7)) << 3);
            bf16x8 kh0 = *reinterpret_cast<const bf16x8*>(&KhiB[o0]);
            bf16x8 kl0 = *reinterpret_cast<const bf16x8*>(&KloB[o0]);
            bf16x8 kh1 = *reinterpret_cast<const bf16x8*>(&KhiB[o1]);
            bf16x8 kl1 = *reinterpret_cast<const bf16x8*>(&KloB[o1]);
            #pragma unroll
            for (int qg = 0; qg < 2; ++qg) {
                // two independent 3-deep chains, then one add
                f32x4 sa = {}, sb = {};
                sa = __builtin_amdgcn_mfma_f32_16x16x32_bf16(kh0, qh[qg][0], sa, 0, 0, 0);
                sb = __builtin_amdgcn_mfma_f32_16x16x32_bf16(kh1, qh[qg][1], sb, 0, 0, 0);
                sa = __builtin_amdgcn_mfma_f32_16x16x32_bf16(kl0, qh[qg][0], sa, 0, 0, 0);
                sb = __builtin_amdgcn_mfma_f32_16x16x32_bf16(kl1, qh[qg][1], sb, 0, 0, 0);
                sa = __builtin_amdgcn_mfma_f32_16x16x32_bf16(kh0, ql[qg][0], sa, 0, 0, 0);
                sb = __builtin_amdgcn_mfma_f32_16x16x32_bf16(kh1, ql[qg][1], sb, 0, 0, 0);
                f32x4 st = sa + sb;

                f32x4 pp;
                #pragma unroll
                for (int r2 = 0; r2 < 4; ++r2) pp[r2] = exp2f(st[r2]);
                l_lane[qg] += (pp[0] + pp[1]) + (pp[2] + pp[3]);

                bf16x4 p4;
                #pragma unroll
                for (int r2 = 0; r2 < 4; ++r2) p4[r2] = (__bf16)pp[r2];
                const int prow = w * 32 + qg * 16 + n16;
                const int ch2 = kg * 2 + (quad >> 1);
                const int off = prow * 64 + ((ch2 ^ (prow & 7)) << 3) + (quad & 1) * 4;
                *reinterpret_cast<bf16x4*>(&Ps[off]) = p4;
            }
        }

        bf16x8 pa[2][2];
        #pragma unroll
        for (int qg = 0; qg < 2; ++qg) {
            const int prow = w * 32 + qg * 16 + n16;
            #pragma unroll
            for (int s2 = 0; s2 < 2; ++s2)
                pa[qg][s2] = *reinterpret_cast<const bf16x8*>(
                    &Ps[prow * 64 + (((s2 * 4 + quad) ^ (prow & 7)) << 3)]);
        }
        #pragma unroll
        for (int c = 0; c < 4; ++c) {
            const int vr = c * 16 + n16;
            bf16x8 vb0 = *reinterpret_cast<const bf16x8*>(
                &VtB[vr * 64 + ((quad ^ (vr & 7)) << 3)]);
            bf16x8 vb1 = *reinterpret_cast<const bf16x8*>(
                &VtB[vr * 64 + (((4 + quad) ^ (vr & 7)) << 3)]);
            #pragma unroll
            for (int qg = 0; qg < 2; ++qg) {
                o[qg][c] = __builtin_amdgcn_mfma_f32_16x16x32_bf16(pa[qg][0], vb0, o[qg][c], 0, 0, 0);
                o[qg][c] = __builtin_amdgcn_mfma_f32_16x16x32_bf16(pa[qg][1], vb1, o[qg][c], 0, 0, 0);
            }
        }

        __builtin_amdgcn_s_barrier();
        __builtin_amdgcn_sched_barrier(0);
    }

    #pragma unroll
    for (int qg = 0; qg < 2; ++qg) {
        l_lane[qg] += __shfl_xor(l_lane[qg], 16, 64);
        l_lane[qg] += __shfl_xor(l_lane[qg], 32, 64);
    }

    const int b = bh >> 4, hh = bh & 15;
    #pragma unroll
    for (int qg = 0; qg < 2; ++qg) {
        #pragma unroll
        for (int r2 = 0; r2 < 4; ++r2) {
            const float l = __shfl(l_lane[qg], (quad << 4) + quad * 4 + r2, 64);
            const float linv = 1.0f / l;
            const int srow = qt * 128 + w * 32 + qg * 16 + quad * 4 + r2;
            const size_t rowoff = (size_t)(b * SEQ + srow) * (2*DM);
            #pragma unroll
            for (int c = 0; c < 4; ++c) {
                const int col = hh * HD + c * 16 + n16;
                float v = o[qg][c][r2] * linv;
                __bf16 h = (__bf16)v;
                ctx2[rowoff + col] = h;
                ctx2[rowoff + DM + col] = (__bf16)(v - (float)h);
            }
        }
    }
}

extern "C" void kernel_launch(void* const* d_in, const int* in_sizes, int n_in,
                              void* d_out, int out_size, void* d_ws, size_t ws_size,
                              hipStream_t stream)
{
    const float* x    = (const float*)d_in[0];
    const float* Wqkv = (const float*)d_in[1];
    const float* bqkv = (const float*)d_in[2];
    const float* Wout = (const float*)d_in[3];
    const float* bout = (const float*)d_in[4];
    float* out = (float*)d_out;

    // ws layout (MB): 0-16 xs (alias ctx2) | 16-28 wqt | 28-32 wot |
    //                 32-48 qs | 48-56 khi | 56-64 klo | 64-72 vt
    char* ws = (char*)d_ws;
    __bf16* xs   = (__bf16*)(ws);
    __bf16* ctx2 = xs;
    __bf16* wqt  = (__bf16*)(ws + (size_t)16 * 1024 * 1024);
    __bf16* wot  = (__bf16*)(ws + (size_t)28 * 1024 * 1024);
    __bf16* qsb  = (__bf16*)(ws + (size_t)32 * 1024 * 1024);
    __bf16* khi  = (__bf16*)(ws + (size_t)48 * 1024 * 1024);
    __bf16* klo  = (__bf16*)(ws + (size_t)56 * 1024 * 1024);
    __bf16* vt   = (__bf16*)(ws + (size_t)64 * 1024 * 1024);

    prep_kernel<<<dim3(5120), 256, 0, stream>>>(x, Wqkv, Wout, xs, wqt, wot);
    gemm_qkv_kernel<<<dim3(192), 512, 0, stream>>>(
        xs, wqt, bqkv, qsb, khi, klo, vt);
    flash_attn_v5_kernel<<<dim3(512), 256, 0, stream>>>(qsb, khi, klo, vt, ctx2);
    gemm_out_kernel<<<dim3(M_TOT / 128, DM / 64), 256, 0, stream>>>(
        ctx2, wot, bout, out);
}

// Round 5
// 289.798 us; speedup vs baseline: 1.2162x; 1.2162x over previous
//
#include <hip/hip_runtime.h>
#include <stdint.h>

// SelfAttention: bf16x3 MFMA GEMMs + DMA-staged MFMA flash attention.
// R14->R15: flash reverted to the proven R13 batch-of-2-tiles structure
// (R14's 1-tile-lead vmcnt pipeline measured 156us vs 94.6 -- the per-tile
// fences destroyed compiler overlap and the lead was < HBM latency anyway).
// qkv reverted to R13 per-phase staging (proven 94.9us) + ONE probe: an
// m201-style second barrier after each phase's MFMA cluster (phase-locking
// so all waves' ds_reads cluster, then all MFMAs cluster).

#define BATCH 2
#define SEQ 2048
#define DM 1024
#define NH 16
#define HD 64
#define M_TOT 4096
// 1/sqrt(HD) * log2(e): scores come out in base-2 domain
#define QSCALE 0.18033688011112042f

typedef __bf16 bf16x8 __attribute__((ext_vector_type(8)));
typedef __bf16 bf16x4 __attribute__((ext_vector_type(4)));
typedef float  f32x4  __attribute__((ext_vector_type(4)));

__device__ __forceinline__ void gld_lds16(const void* g, void* l) {
    __builtin_amdgcn_global_load_lds(
        (const __attribute__((address_space(1))) uint32_t*)g,
        (__attribute__((address_space(3))) uint32_t*)l, 16, 0, 0);
}

// ---------------- prep: fp32 -> bf16 hi/lo splits (x, Wqkv^T, Wout^T) -------
__launch_bounds__(256)
__global__ void prep_kernel(const float* __restrict__ x,
                            const float* __restrict__ Wqkv,
                            const float* __restrict__ Wout,
                            __bf16* __restrict__ xs,
                            __bf16* __restrict__ wqt,
                            __bf16* __restrict__ wot)
{
    __shared__ float T[64][69];
    const int tid = threadIdx.x;
    const int blk = blockIdx.x;

    if (blk < 4096) {
        const int i  = blk * 256 + tid;
        const int m  = i >> 8;
        const int c4 = (i & 255) * 4;
        float4 v = *reinterpret_cast<const float4*>(&x[(size_t)m * DM + c4]);
        float a[4] = {v.x, v.y, v.z, v.w};
        bf16x4 hi, lo;
        #pragma unroll
        for (int j = 0; j < 4; ++j) {
            __bf16 h = (__bf16)a[j];
            hi[j] = h;
            lo[j] = (__bf16)(a[j] - (float)h);
        }
        *reinterpret_cast<bf16x4*>(&xs[(size_t)m * (2*DM) + c4]) = hi;
        *reinterpret_cast<bf16x4*>(&xs[(size_t)m * (2*DM) + DM + c4]) = lo;
        return;
    }

    const int bb = (blk < 4864) ? blk - 4096 : blk - 4864;
    const float* W = (blk < 4864) ? Wqkv : Wout;
    __bf16* Wt     = (blk < 4864) ? wqt  : wot;
    const int N    = (blk < 4864) ? 3 * DM : DM;
    const int k0 = (bb & 15) * 64, n0 = (bb >> 4) * 64;

    {
        const int kr = tid >> 4, c4 = (tid & 15) * 4;
        #pragma unroll
        for (int i = 0; i < 4; ++i) {
            float4 v = *reinterpret_cast<const float4*>(
                &W[(size_t)(k0 + kr + 16 * i) * N + n0 + c4]);
            *reinterpret_cast<float4*>(&T[kr + 16 * i][c4]) = v;
        }
    }
    __syncthreads();
    {
        const int n = tid >> 2, kc = (tid & 3) * 16;
        __bf16 hi[16], lo[16];
        #pragma unroll
        for (int j = 0; j < 16; ++j) {
            float v = T[kc + j][n];
            __bf16 h = (__bf16)v;
            hi[j] = h;
            lo[j] = (__bf16)(v - (float)h);
        }
        const size_t ro = (size_t)(n0 + n) * (2*DM) + k0 + kc;
        *reinterpret_cast<bf16x8*>(&Wt[ro])          = *reinterpret_cast<bf16x8*>(&hi[0]);
        *reinterpret_cast<bf16x8*>(&Wt[ro + 8])      = *reinterpret_cast<bf16x8*>(&hi[8]);
        *reinterpret_cast<bf16x8*>(&Wt[ro + DM])     = *reinterpret_cast<bf16x8*>(&lo[0]);
        *reinterpret_cast<bf16x8*>(&Wt[ro + DM + 8]) = *reinterpret_cast<bf16x8*>(&lo[8]);
    }
}

// ---------------- QKV GEMM: 256x256 4-phase, BK=64, virtual-K'=3072 ---------
// 512 threads = 8 waves (2M x 4N). Per wave 128x64 output = acc[8][4].
// LDS: 2 x (A 256x64 + B 256x64) bf16 = 128KB, xor-8 swizzled 64-wide rows.
// R13 staging (stage half p at phase p, vmcnt(2) at phase 0) + R15 probe:
// end-of-phase barrier after each MFMA cluster (m201 phase-locking).
__launch_bounds__(512, 2)
__global__ void gemm_qkv_kernel(const __bf16* __restrict__ A,
                                const __bf16* __restrict__ Bt,
                                const float* __restrict__ bias,
                                __bf16* __restrict__ qs,
                                __bf16* __restrict__ khi_g,
                                __bf16* __restrict__ klo_g,
                                __bf16* __restrict__ vt_g)
{
    __shared__ __align__(16) __bf16 pool[65536];   // 128 KB

    const int tid  = threadIdx.x;
    const int w    = tid >> 6;            // 0..7
    const int lane = tid & 63;
    const int n16  = lane & 15;
    const int quad = lane >> 4;

    // bijective XCD swizzle over 192 blocks (192 % 8 == 0)
    const int wg = (blockIdx.x & 7) * 24 + (blockIdx.x >> 3);
    const int bm = (wg & 15) * 256;       // 16 M-tiles
    const int bn = (wg >> 4) * 256;       // 12 N-tiles

    const int wm = (w >> 2) * 128;        // wave M offset (2)
    const int wn = (w & 3) * 64;          // wave N offset (4)

    const int r0 = tid >> 3;                       // 0..63 (slot1 = r0+64)
    const int c0 = ((tid & 7) ^ (r0 & 7));         // col chunk (both slots)

    auto stage = [&](int p, int kcol, int nbuf) {
        __bf16* dst = pool + nbuf * 32768 + p * 8192;
        const __bf16* gsrc = (p < 2)
            ? A  + (size_t)(bm + p * 128) * (2*DM) + kcol
            : Bt + (size_t)(bn + (p - 2) * 128) * (2*DM) + kcol;
        gld_lds16(gsrc + (size_t)r0 * (2*DM) + c0 * 8,        dst + (size_t)tid * 8);
        gld_lds16(gsrc + (size_t)(r0 + 64) * (2*DM) + c0 * 8, dst + (size_t)(512 + tid) * 8);
    };

    // fragment read addressing (xor-8 swizzle, conflict-even)
    const int rowA = (wm + n16) * 64;
    const int rowB = (wn + n16) * 64;
    const int sx0 = ((quad)     ^ (n16 & 7)) << 3;   // k-half 0
    const int sx1 = ((4 + quad) ^ (n16 & 7)) << 3;   // k-half 1

    f32x4 acc[8][4] = {};
    bf16x8 af[4][2], bf0[2][2], bf1[2][2];

    // prologue: stage tile 0 fully into buf 0
    stage(0, 0, 0); stage(1, 0, 0); stage(2, 0, 0); stage(3, 0, 0);

    #pragma unroll 2
    for (int t = 0; t < 48; ++t) {
        const int buf = t & 1;
        const __bf16* bufA = pool + buf * 32768;
        const __bf16* bufB = bufA + 16384;
        const int nbuf = buf ^ 1;
        const bool pre = (t < 47);
        const int tt = t + 1;
        const int a_k = (tt < 16) ? tt * 64 : tt * 64 - DM;       // [xh|xh|xl]
        const int b_k = (tt < 32) ? tt * 64 : tt * 64 - 2 * DM;   // [wh|wl|wh]

        // ---- phase 0: quadrant (M0,N0) ----
        if (pre) {
            stage(0, a_k, nbuf);
            asm volatile("s_waitcnt vmcnt(2)" ::: "memory");
        } else {
            asm volatile("s_waitcnt vmcnt(0)" ::: "memory");
        }
        __builtin_amdgcn_s_barrier();
        __builtin_amdgcn_sched_barrier(0);
        #pragma unroll
        for (int i = 0; i < 4; ++i) {
            af[i][0] = *reinterpret_cast<const bf16x8*>(bufA + rowA + i * 1024 + sx0);
            af[i][1] = *reinterpret_cast<const bf16x8*>(bufA + rowA + i * 1024 + sx1);
        }
        #pragma unroll
        for (int j = 0; j < 2; ++j) {
            bf0[j][0] = *reinterpret_cast<const bf16x8*>(bufB + rowB + j * 1024 + sx0);
            bf0[j][1] = *reinterpret_cast<const bf16x8*>(bufB + rowB + j * 1024 + sx1);
        }
        asm volatile("s_waitcnt lgkmcnt(0)" ::: "memory");
        __builtin_amdgcn_sched_barrier(0);
        __builtin_amdgcn_s_setprio(1);
        #pragma unroll
        for (int i = 0; i < 4; ++i)
            #pragma unroll
            for (int j = 0; j < 2; ++j) {
                acc[i][j] = __builtin_amdgcn_mfma_f32_16x16x32_bf16(af[i][0], bf0[j][0], acc[i][j], 0, 0, 0);
                acc[i][j] = __builtin_amdgcn_mfma_f32_16x16x32_bf16(af[i][1], bf0[j][1], acc[i][j], 0, 0, 0);
            }
        __builtin_amdgcn_s_setprio(0);
        __builtin_amdgcn_s_barrier();          // R15 probe: phase-lock
        __builtin_amdgcn_sched_barrier(0);

        // ---- phase 1: quadrant (M0,N1) ----
        #pragma unroll
        for (int j = 0; j < 2; ++j) {
            bf1[j][0] = *reinterpret_cast<const bf16x8*>(bufB + rowB + (2 + j) * 1024 + sx0);
            bf1[j][1] = *reinterpret_cast<const bf16x8*>(bufB + rowB + (2 + j) * 1024 + sx1);
        }
        if (pre) stage(1, a_k, nbuf);
        __builtin_amdgcn_s_barrier();
        __builtin_amdgcn_sched_barrier(0);
        asm volatile("s_waitcnt lgkmcnt(0)" ::: "memory");
        __builtin_amdgcn_sched_barrier(0);
        __builtin_amdgcn_s_setprio(1);
        #pragma unroll
        for (int i = 0; i < 4; ++i)
            #pragma unroll
            for (int j = 0; j < 2; ++j) {
                acc[i][2 + j] = __builtin_amdgcn_mfma_f32_16x16x32_bf16(af[i][0], bf1[j][0], acc[i][2 + j], 0, 0, 0);
                acc[i][2 + j] = __builtin_amdgcn_mfma_f32_16x16x32_bf16(af[i][1], bf1[j][1], acc[i][2 + j], 0, 0, 0);
            }
        __builtin_amdgcn_s_setprio(0);
        __builtin_amdgcn_s_barrier();          // R15 probe: phase-lock
        __builtin_amdgcn_sched_barrier(0);

        // ---- phase 2: quadrant (M1,N0) ----
        #pragma unroll
        for (int i = 0; i < 4; ++i) {
            af[i][0] = *reinterpret_cast<const bf16x8*>(bufA + rowA + (4 + i) * 1024 + sx0);
            af[i][1] = *reinterpret_cast<const bf16x8*>(bufA + rowA + (4 + i) * 1024 + sx1);
        }
        if (pre) stage(2, b_k, nbuf);
        __builtin_amdgcn_s_barrier();
        __builtin_amdgcn_sched_barrier(0);
        asm volatile("s_waitcnt lgkmcnt(0)" ::: "memory");
        __builtin_amdgcn_sched_barrier(0);
        __builtin_amdgcn_s_setprio(1);
        #pragma unroll
        for (int i = 0; i < 4; ++i)
            #pragma unroll
            for (int j = 0; j < 2; ++j) {
                acc[4 + i][j] = __builtin_amdgcn_mfma_f32_16x16x32_bf16(af[i][0], bf0[j][0], acc[4 + i][j], 0, 0, 0);
                acc[4 + i][j] = __builtin_amdgcn_mfma_f32_16x16x32_bf16(af[i][1], bf0[j][1], acc[4 + i][j], 0, 0, 0);
            }
        __builtin_amdgcn_s_setprio(0);
        __builtin_amdgcn_s_barrier();          // R15 probe: phase-lock
        __builtin_amdgcn_sched_barrier(0);

        // ---- phase 3: quadrant (M1,N1) ----
        if (pre) stage(3, b_k, nbuf);
        __builtin_amdgcn_s_barrier();
        __builtin_amdgcn_sched_barrier(0);
        __builtin_amdgcn_s_setprio(1);
        #pragma unroll
        for (int i = 0; i < 4; ++i)
            #pragma unroll
            for (int j = 0; j < 2; ++j) {
                acc[4 + i][2 + j] = __builtin_amdgcn_mfma_f32_16x16x32_bf16(af[i][0], bf1[j][0], acc[4 + i][2 + j], 0, 0, 0);
                acc[4 + i][2 + j] = __builtin_amdgcn_mfma_f32_16x16x32_bf16(af[i][1], bf1[j][1], acc[4 + i][2 + j], 0, 0, 0);
            }
        __builtin_amdgcn_s_setprio(0);
        __builtin_amdgcn_s_barrier();          // R15 probe: phase-lock
        __builtin_amdgcn_sched_barrier(0);
    }

    // Fenced barrier before reusing pool as epilogue scratch (race fix, R13).
    __syncthreads();

    // ---- epilogue: wave-private LDS transpose, coalesced b128 stores ----
    const int colb = bn + wn;
    const int part = colb >> 10;              // 0:Q 1:K 2:V (block-uniform)
    const int hh   = (colb & 1023) >> 6;

    float bv[4];
    #pragma unroll
    for (int j = 0; j < 4; ++j) bv[j] = bias[colb + j * 16 + n16];

    __bf16* scrH = pool + w * 4608;
    __bf16* scrL = scrH + 2304;
    const int lr = lane & 31, hc = lane >> 5;

    #pragma unroll
    for (int mi = 0; mi < 2; ++mi) {
        const int brow = bm + wm + mi * 64;
        const int b    = brow >> 11;
        const int s0   = brow & 2047;
        const int bh   = b * NH + hh;
        const int kt   = s0 >> 6;
        const size_t tb = ((size_t)bh * 32 + kt) * 4096;

        #pragma unroll
        for (int p = 0; p < 2; ++p) {
            if (part == 2) {
                #pragma unroll
                for (int jj = 0; jj < 2; ++jj) {
                    const int j = 2 * p + jj;
                    #pragma unroll
                    for (int i = 0; i < 4; ++i) {
                        bf16x4 v4;
                        #pragma unroll
                        for (int r = 0; r < 4; ++r)
                            v4[r] = (__bf16)(acc[4 * mi + i][j][r] + bv[j]);
                        *reinterpret_cast<bf16x4*>(
                            &scrH[(jj * 16 + n16) * 72 + i * 16 + quad * 4]) = v4;
                    }
                }
            } else {
                #pragma unroll
                for (int ii = 0; ii < 2; ++ii) {
                    const int i = 2 * p + ii;
                    #pragma unroll
                    for (int j = 0; j < 4; ++j) {
                        #pragma unroll
                        for (int r = 0; r < 4; ++r) {
                            float val = acc[4 * mi + i][j][r] + bv[j];
                            if (part == 0) val *= QSCALE;   // 1/sqrt(HD)*log2e
                            __bf16 h = (__bf16)val;
                            const int so = (ii * 16 + quad * 4 + r) * 72 + j * 16 + n16;
                            scrH[so] = h;
                            scrL[so] = (__bf16)(val - (float)h);
                        }
                    }
                }
            }
            __syncthreads();

            if (part == 0) {
                const size_t qbase = ((size_t)bh * SEQ + s0 + 32 * p + lr) * 128;
                #pragma unroll
                for (int t = 0; t < 4; ++t) {
                    const int ch = hc * 4 + t;
                    *reinterpret_cast<bf16x8*>(&qs[qbase + ch * 8]) =
                        *reinterpret_cast<const bf16x8*>(&scrH[lr * 72 + ch * 8]);
                    *reinterpret_cast<bf16x8*>(&qs[qbase + 64 + ch * 8]) =
                        *reinterpret_cast<const bf16x8*>(&scrL[lr * 72 + ch * 8]);
                }
            } else if (part == 1) {
                const int kr = 32 * p + lr;
                #pragma unroll
                for (int t = 0; t < 4; ++t) {
                    const int ch = hc * 4 + t;
                    const int src = (ch ^ (lr & 7)) * 8;
                    *reinterpret_cast<bf16x8*>(&khi_g[tb + kr * 64 + ch * 8]) =
                        *reinterpret_cast<const bf16x8*>(&scrH[lr * 72 + src]);
                    *reinterpret_cast<bf16x8*>(&klo_g[tb + kr * 64 + ch * 8]) =
                        *reinterpret_cast<const bf16x8*>(&scrL[lr * 72 + src]);
                }
            } else {
                const int d = 32 * p + lr;
                #pragma unroll
                for (int t = 0; t < 4; ++t) {
                    const int ch = hc * 4 + t;
                    const int src = (ch ^ (lr & 7)) * 8;
                    *reinterpret_cast<bf16x8*>(&vt_g[tb + d * 64 + ch * 8]) =
                        *reinterpret_cast<const bf16x8*>(&scrH[lr * 72 + src]);
                }
            }
            __syncthreads();
        }
    }
}

// ---------------- out-proj GEMM (bf16x3, 128x64 tile, fused-K loop) ----------
__launch_bounds__(256)
__global__ void gemm_out_kernel(const __bf16* __restrict__ A,
                                const __bf16* __restrict__ Bt,
                                const float* __restrict__ bias,
                                float* __restrict__ out)
{
    __shared__ __align__(16) __bf16 AsH[128 * 32];
    __shared__ __align__(16) __bf16 AsL[128 * 32];
    __shared__ __align__(16) __bf16 BsH[64 * 32];
    __shared__ __align__(16) __bf16 BsL[64 * 32];

    const int tid  = threadIdx.x;
    const int w    = tid >> 6;
    const int lane = tid & 63;
    const int n16  = lane & 15;
    const int quad = lane >> 4;
    const int bm = blockIdx.x * 128, bn = blockIdx.y * 64;
    const int wm = (w & 1) * 64,     wn = (w >> 1) * 32;

    const int srow = tid >> 2, sc = (tid & 3) * 8;
    const __bf16* Ar = A  + (size_t)(bm + srow) * (2*DM) + sc;
    const __bf16* Br = Bt + (size_t)(bn + srow) * (2*DM) + sc;   // rows 0..63

    f32x4 acc[4][2] = {};

    for (int k0 = 0; k0 < DM; k0 += 32) {
        __syncthreads();
        gld_lds16(Ar + k0,                         &AsH[(size_t)tid * 8]);
        gld_lds16(Ar + k0 + (size_t)64*2*DM,       &AsH[(size_t)(256 + tid) * 8]);
        gld_lds16(Ar + DM + k0,                    &AsL[(size_t)tid * 8]);
        gld_lds16(Ar + DM + k0 + (size_t)64*2*DM,  &AsL[(size_t)(256 + tid) * 8]);
        gld_lds16(Br + k0,                         &BsH[(size_t)tid * 8]);
        gld_lds16(Br + DM + k0,                    &BsL[(size_t)tid * 8]);
        __syncthreads();

        bf16x8 afh[4], afl[4], bfh[2], bfl[2];
        #pragma unroll
        for (int i = 0; i < 4; ++i) {
            const int ro = (wm + i*16 + n16) * 32 + quad * 8;
            afh[i] = *reinterpret_cast<const bf16x8*>(&AsH[ro]);
            afl[i] = *reinterpret_cast<const bf16x8*>(&AsL[ro]);
        }
        #pragma unroll
        for (int j = 0; j < 2; ++j) {
            const int ro = (wn + j*16 + n16) * 32 + quad * 8;
            bfh[j] = *reinterpret_cast<const bf16x8*>(&BsH[ro]);
            bfl[j] = *reinterpret_cast<const bf16x8*>(&BsL[ro]);
        }
        #pragma unroll
        for (int i = 0; i < 4; ++i)
            #pragma unroll
            for (int j = 0; j < 2; ++j) {
                acc[i][j] = __builtin_amdgcn_mfma_f32_16x16x32_bf16(afh[i], bfh[j], acc[i][j], 0, 0, 0);
                acc[i][j] = __builtin_amdgcn_mfma_f32_16x16x32_bf16(afh[i], bfl[j], acc[i][j], 0, 0, 0);
                acc[i][j] = __builtin_amdgcn_mfma_f32_16x16x32_bf16(afl[i], bfh[j], acc[i][j], 0, 0, 0);
            }
    }

    #pragma unroll
    for (int j = 0; j < 2; ++j) {
        const int col = bn + wn + j * 16 + n16;
        const float bvv = bias[col];
        #pragma unroll
        for (int i = 0; i < 4; ++i) {
            const int row0 = bm + wm + i * 16 + quad * 4;
            #pragma unroll
            for (int r = 0; r < 4; ++r)
                out[(size_t)(row0 + r) * DM + col] = acc[i][j][r] + bvv;
        }
    }
}

// ---------------- Flash attention: G=2, 2-tile staging per barrier ----------
// grid 512 (XCD-swizzled), 4 waves. Wave w owns queries qt*128 + w*32 .. +31.
// Two 24KB K/V tiles staged per barrier pair (16 drains instead of 32);
// 64KB LDS still allows the grid-limited 2 blocks/CU. (R13 proven form.)
__launch_bounds__(256, 2)
__global__ void flash_attn_v5_kernel(const __bf16* __restrict__ qs,
                                     const __bf16* __restrict__ khi_g,
                                     const __bf16* __restrict__ klo_g,
                                     const __bf16* __restrict__ vt_g,
                                     __bf16* __restrict__ ctx2)
{
    __shared__ __align__(16) __bf16 Khi[2][4096];
    __shared__ __align__(16) __bf16 Klo[2][4096];
    __shared__ __align__(16) __bf16 Vt [2][4096];
    __shared__ __align__(16) __bf16 Ps [8192];   // 128 q-rows x 64, swizzled

    const int tid  = threadIdx.x;
    const int w    = tid >> 6;            // 0..3
    const int lane = tid & 63;
    const int n16  = lane & 15;
    const int quad = lane >> 4;
    const int bid  = blockIdx.x;
    const int bh = (bid & 7) * 4 + (bid >> 7);
    const int qt = (bid >> 3) & 15;

    bf16x8 qh[2][2], ql[2][2];
    #pragma unroll
    for (int qg = 0; qg < 2; ++qg) {
        const size_t qrow =
            ((size_t)bh * SEQ + qt * 128 + w * 32 + qg * 16 + n16) * 128;
        #pragma unroll
        for (int s2 = 0; s2 < 2; ++s2) {
            qh[qg][s2] = *reinterpret_cast<const bf16x8*>(&qs[qrow + s2 * 32 + quad * 8]);
            ql[qg][s2] = *reinterpret_cast<const bf16x8*>(&qs[qrow + 64 + s2 * 32 + quad * 8]);
        }
    }

    f32x4 o[2][4] = {};
    float l_lane[2] = {};

    for (int kt2 = 0; kt2 < 16; ++kt2) {
        __syncthreads();
        {
            const int buf = w >> 1;
            const size_t tb = ((size_t)bh * 32 + kt2 * 2 + buf) * 4096;
            #pragma unroll
            for (int t = 0; t < 12; ++t) {
                const int rem = (w & 1) * 12 + t;    // 0..23
                const int arr = rem >> 3, sub = rem & 7;
                const int eo = sub * 512 + lane * 8;
                const __bf16* g = (arr == 0 ? khi_g : arr == 1 ? klo_g : vt_g) + tb + eo;
                __bf16* l = (arr == 0 ? Khi[buf] : arr == 1 ? Klo[buf] : Vt[buf]) + eo;
                gld_lds16(g, l);
            }
        }
        __syncthreads();

        #pragma unroll
        for (int hf = 0; hf < 2; ++hf) {
            const __bf16* KhiB = Khi[hf];
            const __bf16* KloB = Klo[hf];
            const __bf16* VtB  = Vt[hf];

            #pragma unroll
            for (int kg = 0; kg < 4; ++kg) {
                const int r = kg * 16 + n16;
                const int o0 = r * 64 + ((quad ^ (r & 7)) << 3);
                const int o1 = r * 64 + (((4 + quad) ^ (r & 7)) << 3);
                bf16x8 kh0 = *reinterpret_cast<const bf16x8*>(&KhiB[o0]);
                bf16x8 kl0 = *reinterpret_cast<const bf16x8*>(&KloB[o0]);
                bf16x8 kh1 = *reinterpret_cast<const bf16x8*>(&KhiB[o1]);
                bf16x8 kl1 = *reinterpret_cast<const bf16x8*>(&KloB[o1]);
                #pragma unroll
                for (int qg = 0; qg < 2; ++qg) {
                    f32x4 sa = {}, sb = {};
                    sa = __builtin_amdgcn_mfma_f32_16x16x32_bf16(kh0, qh[qg][0], sa, 0, 0, 0);
                    sb = __builtin_amdgcn_mfma_f32_16x16x32_bf16(kh1, qh[qg][1], sb, 0, 0, 0);
                    sa = __builtin_amdgcn_mfma_f32_16x16x32_bf16(kl0, qh[qg][0], sa, 0, 0, 0);
                    sb = __builtin_amdgcn_mfma_f32_16x16x32_bf16(kl1, qh[qg][1], sb, 0, 0, 0);
                    sa = __builtin_amdgcn_mfma_f32_16x16x32_bf16(kh0, ql[qg][0], sa, 0, 0, 0);
                    sb = __builtin_amdgcn_mfma_f32_16x16x32_bf16(kh1, ql[qg][1], sb, 0, 0, 0);
                    f32x4 st = sa + sb;

                    f32x4 pp;
                    #pragma unroll
                    for (int r2 = 0; r2 < 4; ++r2) pp[r2] = exp2f(st[r2]);
                    l_lane[qg] += (pp[0] + pp[1]) + (pp[2] + pp[3]);

                    bf16x4 p4;
                    #pragma unroll
                    for (int r2 = 0; r2 < 4; ++r2) p4[r2] = (__bf16)pp[r2];
                    const int prow = w * 32 + qg * 16 + n16;
                    const int ch2 = kg * 2 + (quad >> 1);
                    const int off = prow * 64 + ((ch2 ^ (prow & 7)) << 3) + (quad & 1) * 4;
                    *reinterpret_cast<bf16x4*>(&Ps[off]) = p4;
                }
            }

            bf16x8 pa[2][2];
            #pragma unroll
            for (int qg = 0; qg < 2; ++qg) {
                const int prow = w * 32 + qg * 16 + n16;
                #pragma unroll
                for (int s2 = 0; s2 < 2; ++s2)
                    pa[qg][s2] = *reinterpret_cast<const bf16x8*>(
                        &Ps[prow * 64 + (((s2 * 4 + quad) ^ (prow & 7)) << 3)]);
            }
            #pragma unroll
            for (int c = 0; c < 4; ++c) {
                const int vr = c * 16 + n16;
                bf16x8 vb0 = *reinterpret_cast<const bf16x8*>(
                    &VtB[vr * 64 + ((quad ^ (vr & 7)) << 3)]);
                bf16x8 vb1 = *reinterpret_cast<const bf16x8*>(
                    &VtB[vr * 64 + (((4 + quad) ^ (vr & 7)) << 3)]);
                #pragma unroll
                for (int qg = 0; qg < 2; ++qg) {
                    o[qg][c] = __builtin_amdgcn_mfma_f32_16x16x32_bf16(pa[qg][0], vb0, o[qg][c], 0, 0, 0);
                    o[qg][c] = __builtin_amdgcn_mfma_f32_16x16x32_bf16(pa[qg][1], vb1, o[qg][c], 0, 0, 0);
                }
            }
        }
    }

    #pragma unroll
    for (int qg = 0; qg < 2; ++qg) {
        l_lane[qg] += __shfl_xor(l_lane[qg], 16, 64);
        l_lane[qg] += __shfl_xor(l_lane[qg], 32, 64);
    }

    const int b = bh >> 4, hh = bh & 15;
    #pragma unroll
    for (int qg = 0; qg < 2; ++qg) {
        #pragma unroll
        for (int r2 = 0; r2 < 4; ++r2) {
            const float l = __shfl(l_lane[qg], (quad << 4) + quad * 4 + r2, 64);
            const float linv = 1.0f / l;
            const int srow = qt * 128 + w * 32 + qg * 16 + quad * 4 + r2;
            const size_t rowoff = (size_t)(b * SEQ + srow) * (2*DM);
            #pragma unroll
            for (int c = 0; c < 4; ++c) {
                const int col = hh * HD + c * 16 + n16;
                float v = o[qg][c][r2] * linv;
                __bf16 h = (__bf16)v;
                ctx2[rowoff + col] = h;
                ctx2[rowoff + DM + col] = (__bf16)(v - (float)h);
            }
        }
    }
}

extern "C" void kernel_launch(void* const* d_in, const int* in_sizes, int n_in,
                              void* d_out, int out_size, void* d_ws, size_t ws_size,
                              hipStream_t stream)
{
    const float* x    = (const float*)d_in[0];
    const float* Wqkv = (const float*)d_in[1];
    const float* bqkv = (const float*)d_in[2];
    const float* Wout = (const float*)d_in[3];
    const float* bout = (const float*)d_in[4];
    float* out = (float*)d_out;

    // ws layout (MB): 0-16 xs (alias ctx2) | 16-28 wqt | 28-32 wot |
    //                 32-48 qs | 48-56 khi | 56-64 klo | 64-72 vt
    char* ws = (char*)d_ws;
    __bf16* xs   = (__bf16*)(ws);
    __bf16* ctx2 = xs;
    __bf16* wqt  = (__bf16*)(ws + (size_t)16 * 1024 * 1024);
    __bf16* wot  = (__bf16*)(ws + (size_t)28 * 1024 * 1024);
    __bf16* qsb  = (__bf16*)(ws + (size_t)32 * 1024 * 1024);
    __bf16* khi  = (__bf16*)(ws + (size_t)48 * 1024 * 1024);
    __bf16* klo  = (__bf16*)(ws + (size_t)56 * 1024 * 1024);
    __bf16* vt   = (__bf16*)(ws + (size_t)64 * 1024 * 1024);

    prep_kernel<<<dim3(5120), 256, 0, stream>>>(x, Wqkv, Wout, xs, wqt, wot);
    gemm_qkv_kernel<<<dim3(192), 512, 0, stream>>>(
        xs, wqt, bqkv, qsb, khi, klo, vt);
    flash_attn_v5_kernel<<<dim3(512), 256, 0, stream>>>(qsb, khi, klo, vt, ctx2);
    gemm_out_kernel<<<dim3(M_TOT / 128, DM / 64), 256, 0, stream>>>(
        ctx2, wot, bout, out);
}

// Round 6
// 282.294 us; speedup vs baseline: 1.2485x; 1.0266x over previous
//
#include <hip/hip_runtime.h>
#include <stdint.h>

// SelfAttention: bf16x3 MFMA GEMMs + DMA-staged MFMA flash attention.
// R15->R16: (1) qkv reverted to proven R13 form (phase-lock barrier probe
// measured 102.3 vs 94.9 -- falsified). (2) flash: 4 waves/32 q-rows ->
// 8 waves/16 q-rows per wave (512 threads). Same grid 512, same staging
// volume and math; waves/SIMD 2 -> 4 doubles latency hiding of the serial
// QK->softmax->Ps->PV chain. LDS 64KB unchanged -> still 2 blocks/CU.

#define BATCH 2
#define SEQ 2048
#define DM 1024
#define NH 16
#define HD 64
#define M_TOT 4096
// 1/sqrt(HD) * log2(e): scores come out in base-2 domain
#define QSCALE 0.18033688011112042f

typedef __bf16 bf16x8 __attribute__((ext_vector_type(8)));
typedef __bf16 bf16x4 __attribute__((ext_vector_type(4)));
typedef float  f32x4  __attribute__((ext_vector_type(4)));

__device__ __forceinline__ void gld_lds16(const void* g, void* l) {
    __builtin_amdgcn_global_load_lds(
        (const __attribute__((address_space(1))) uint32_t*)g,
        (__attribute__((address_space(3))) uint32_t*)l, 16, 0, 0);
}

// ---------------- prep: fp32 -> bf16 hi/lo splits (x, Wqkv^T, Wout^T) -------
__launch_bounds__(256)
__global__ void prep_kernel(const float* __restrict__ x,
                            const float* __restrict__ Wqkv,
                            const float* __restrict__ Wout,
                            __bf16* __restrict__ xs,
                            __bf16* __restrict__ wqt,
                            __bf16* __restrict__ wot)
{
    __shared__ float T[64][69];
    const int tid = threadIdx.x;
    const int blk = blockIdx.x;

    if (blk < 4096) {
        const int i  = blk * 256 + tid;
        const int m  = i >> 8;
        const int c4 = (i & 255) * 4;
        float4 v = *reinterpret_cast<const float4*>(&x[(size_t)m * DM + c4]);
        float a[4] = {v.x, v.y, v.z, v.w};
        bf16x4 hi, lo;
        #pragma unroll
        for (int j = 0; j < 4; ++j) {
            __bf16 h = (__bf16)a[j];
            hi[j] = h;
            lo[j] = (__bf16)(a[j] - (float)h);
        }
        *reinterpret_cast<bf16x4*>(&xs[(size_t)m * (2*DM) + c4]) = hi;
        *reinterpret_cast<bf16x4*>(&xs[(size_t)m * (2*DM) + DM + c4]) = lo;
        return;
    }

    const int bb = (blk < 4864) ? blk - 4096 : blk - 4864;
    const float* W = (blk < 4864) ? Wqkv : Wout;
    __bf16* Wt     = (blk < 4864) ? wqt  : wot;
    const int N    = (blk < 4864) ? 3 * DM : DM;
    const int k0 = (bb & 15) * 64, n0 = (bb >> 4) * 64;

    {
        const int kr = tid >> 4, c4 = (tid & 15) * 4;
        #pragma unroll
        for (int i = 0; i < 4; ++i) {
            float4 v = *reinterpret_cast<const float4*>(
                &W[(size_t)(k0 + kr + 16 * i) * N + n0 + c4]);
            *reinterpret_cast<float4*>(&T[kr + 16 * i][c4]) = v;
        }
    }
    __syncthreads();
    {
        const int n = tid >> 2, kc = (tid & 3) * 16;
        __bf16 hi[16], lo[16];
        #pragma unroll
        for (int j = 0; j < 16; ++j) {
            float v = T[kc + j][n];
            __bf16 h = (__bf16)v;
            hi[j] = h;
            lo[j] = (__bf16)(v - (float)h);
        }
        const size_t ro = (size_t)(n0 + n) * (2*DM) + k0 + kc;
        *reinterpret_cast<bf16x8*>(&Wt[ro])          = *reinterpret_cast<bf16x8*>(&hi[0]);
        *reinterpret_cast<bf16x8*>(&Wt[ro + 8])      = *reinterpret_cast<bf16x8*>(&hi[8]);
        *reinterpret_cast<bf16x8*>(&Wt[ro + DM])     = *reinterpret_cast<bf16x8*>(&lo[0]);
        *reinterpret_cast<bf16x8*>(&Wt[ro + DM + 8]) = *reinterpret_cast<bf16x8*>(&lo[8]);
    }
}

// ---------------- QKV GEMM: 256x256 4-phase, BK=64, virtual-K'=3072 ---------
// 512 threads = 8 waves (2M x 4N). Per wave 128x64 output = acc[8][4].
// LDS: 2 x (A 256x64 + B 256x64) bf16 = 128KB, xor-8 swizzled 64-wide rows.
// R13 proven form: stage half p at phase p, vmcnt(2) at phase 0.
__launch_bounds__(512, 2)
__global__ void gemm_qkv_kernel(const __bf16* __restrict__ A,
                                const __bf16* __restrict__ Bt,
                                const float* __restrict__ bias,
                                __bf16* __restrict__ qs,
                                __bf16* __restrict__ khi_g,
                                __bf16* __restrict__ klo_g,
                                __bf16* __restrict__ vt_g)
{
    __shared__ __align__(16) __bf16 pool[65536];   // 128 KB

    const int tid  = threadIdx.x;
    const int w    = tid >> 6;            // 0..7
    const int lane = tid & 63;
    const int n16  = lane & 15;
    const int quad = lane >> 4;

    // bijective XCD swizzle over 192 blocks (192 % 8 == 0)
    const int wg = (blockIdx.x & 7) * 24 + (blockIdx.x >> 3);
    const int bm = (wg & 15) * 256;       // 16 M-tiles
    const int bn = (wg >> 4) * 256;       // 12 N-tiles

    const int wm = (w >> 2) * 128;        // wave M offset (2)
    const int wn = (w & 3) * 64;          // wave N offset (4)

    const int r0 = tid >> 3;                       // 0..63 (slot1 = r0+64)
    const int c0 = ((tid & 7) ^ (r0 & 7));         // col chunk (both slots)

    auto stage = [&](int p, int kcol, int nbuf) {
        __bf16* dst = pool + nbuf * 32768 + p * 8192;
        const __bf16* gsrc = (p < 2)
            ? A  + (size_t)(bm + p * 128) * (2*DM) + kcol
            : Bt + (size_t)(bn + (p - 2) * 128) * (2*DM) + kcol;
        gld_lds16(gsrc + (size_t)r0 * (2*DM) + c0 * 8,        dst + (size_t)tid * 8);
        gld_lds16(gsrc + (size_t)(r0 + 64) * (2*DM) + c0 * 8, dst + (size_t)(512 + tid) * 8);
    };

    // fragment read addressing (xor-8 swizzle, conflict-even)
    const int rowA = (wm + n16) * 64;
    const int rowB = (wn + n16) * 64;
    const int sx0 = ((quad)     ^ (n16 & 7)) << 3;   // k-half 0
    const int sx1 = ((4 + quad) ^ (n16 & 7)) << 3;   // k-half 1

    f32x4 acc[8][4] = {};
    bf16x8 af[4][2], bf0[2][2], bf1[2][2];

    // prologue: stage tile 0 fully into buf 0
    stage(0, 0, 0); stage(1, 0, 0); stage(2, 0, 0); stage(3, 0, 0);

    #pragma unroll 2
    for (int t = 0; t < 48; ++t) {
        const int buf = t & 1;
        const __bf16* bufA = pool + buf * 32768;
        const __bf16* bufB = bufA + 16384;
        const int nbuf = buf ^ 1;
        const bool pre = (t < 47);
        const int tt = t + 1;
        const int a_k = (tt < 16) ? tt * 64 : tt * 64 - DM;       // [xh|xh|xl]
        const int b_k = (tt < 32) ? tt * 64 : tt * 64 - 2 * DM;   // [wh|wl|wh]

        // ---- phase 0: quadrant (M0,N0) ----
        if (pre) {
            stage(0, a_k, nbuf);
            asm volatile("s_waitcnt vmcnt(2)" ::: "memory");
        } else {
            asm volatile("s_waitcnt vmcnt(0)" ::: "memory");
        }
        __builtin_amdgcn_s_barrier();
        __builtin_amdgcn_sched_barrier(0);
        #pragma unroll
        for (int i = 0; i < 4; ++i) {
            af[i][0] = *reinterpret_cast<const bf16x8*>(bufA + rowA + i * 1024 + sx0);
            af[i][1] = *reinterpret_cast<const bf16x8*>(bufA + rowA + i * 1024 + sx1);
        }
        #pragma unroll
        for (int j = 0; j < 2; ++j) {
            bf0[j][0] = *reinterpret_cast<const bf16x8*>(bufB + rowB + j * 1024 + sx0);
            bf0[j][1] = *reinterpret_cast<const bf16x8*>(bufB + rowB + j * 1024 + sx1);
        }
        asm volatile("s_waitcnt lgkmcnt(0)" ::: "memory");
        __builtin_amdgcn_sched_barrier(0);
        __builtin_amdgcn_s_setprio(1);
        #pragma unroll
        for (int i = 0; i < 4; ++i)
            #pragma unroll
            for (int j = 0; j < 2; ++j) {
                acc[i][j] = __builtin_amdgcn_mfma_f32_16x16x32_bf16(af[i][0], bf0[j][0], acc[i][j], 0, 0, 0);
                acc[i][j] = __builtin_amdgcn_mfma_f32_16x16x32_bf16(af[i][1], bf0[j][1], acc[i][j], 0, 0, 0);
            }
        __builtin_amdgcn_s_setprio(0);

        // ---- phase 1: quadrant (M0,N1) ----
        #pragma unroll
        for (int j = 0; j < 2; ++j) {
            bf1[j][0] = *reinterpret_cast<const bf16x8*>(bufB + rowB + (2 + j) * 1024 + sx0);
            bf1[j][1] = *reinterpret_cast<const bf16x8*>(bufB + rowB + (2 + j) * 1024 + sx1);
        }
        if (pre) stage(1, a_k, nbuf);
        __builtin_amdgcn_s_barrier();
        __builtin_amdgcn_sched_barrier(0);
        asm volatile("s_waitcnt lgkmcnt(0)" ::: "memory");
        __builtin_amdgcn_sched_barrier(0);
        __builtin_amdgcn_s_setprio(1);
        #pragma unroll
        for (int i = 0; i < 4; ++i)
            #pragma unroll
            for (int j = 0; j < 2; ++j) {
                acc[i][2 + j] = __builtin_amdgcn_mfma_f32_16x16x32_bf16(af[i][0], bf1[j][0], acc[i][2 + j], 0, 0, 0);
                acc[i][2 + j] = __builtin_amdgcn_mfma_f32_16x16x32_bf16(af[i][1], bf1[j][1], acc[i][2 + j], 0, 0, 0);
            }
        __builtin_amdgcn_s_setprio(0);

        // ---- phase 2: quadrant (M1,N0) ----
        #pragma unroll
        for (int i = 0; i < 4; ++i) {
            af[i][0] = *reinterpret_cast<const bf16x8*>(bufA + rowA + (4 + i) * 1024 + sx0);
            af[i][1] = *reinterpret_cast<const bf16x8*>(bufA + rowA + (4 + i) * 1024 + sx1);
        }
        if (pre) stage(2, b_k, nbuf);
        __builtin_amdgcn_s_barrier();
        __builtin_amdgcn_sched_barrier(0);
        asm volatile("s_waitcnt lgkmcnt(0)" ::: "memory");
        __builtin_amdgcn_sched_barrier(0);
        __builtin_amdgcn_s_setprio(1);
        #pragma unroll
        for (int i = 0; i < 4; ++i)
            #pragma unroll
            for (int j = 0; j < 2; ++j) {
                acc[4 + i][j] = __builtin_amdgcn_mfma_f32_16x16x32_bf16(af[i][0], bf0[j][0], acc[4 + i][j], 0, 0, 0);
                acc[4 + i][j] = __builtin_amdgcn_mfma_f32_16x16x32_bf16(af[i][1], bf0[j][1], acc[4 + i][j], 0, 0, 0);
            }
        __builtin_amdgcn_s_setprio(0);

        // ---- phase 3: quadrant (M1,N1) ----
        if (pre) stage(3, b_k, nbuf);
        __builtin_amdgcn_s_barrier();
        __builtin_amdgcn_sched_barrier(0);
        __builtin_amdgcn_s_setprio(1);
        #pragma unroll
        for (int i = 0; i < 4; ++i)
            #pragma unroll
            for (int j = 0; j < 2; ++j) {
                acc[4 + i][2 + j] = __builtin_amdgcn_mfma_f32_16x16x32_bf16(af[i][0], bf1[j][0], acc[4 + i][2 + j], 0, 0, 0);
                acc[4 + i][2 + j] = __builtin_amdgcn_mfma_f32_16x16x32_bf16(af[i][1], bf1[j][1], acc[4 + i][2 + j], 0, 0, 0);
            }
        __builtin_amdgcn_s_setprio(0);
    }

    // Fenced barrier before reusing pool as epilogue scratch (race fix, R13).
    __syncthreads();

    // ---- epilogue: wave-private LDS transpose, coalesced b128 stores ----
    const int colb = bn + wn;
    const int part = colb >> 10;              // 0:Q 1:K 2:V (block-uniform)
    const int hh   = (colb & 1023) >> 6;

    float bv[4];
    #pragma unroll
    for (int j = 0; j < 4; ++j) bv[j] = bias[colb + j * 16 + n16];

    __bf16* scrH = pool + w * 4608;
    __bf16* scrL = scrH + 2304;
    const int lr = lane & 31, hc = lane >> 5;

    #pragma unroll
    for (int mi = 0; mi < 2; ++mi) {
        const int brow = bm + wm + mi * 64;
        const int b    = brow >> 11;
        const int s0   = brow & 2047;
        const int bh   = b * NH + hh;
        const int kt   = s0 >> 6;
        const size_t tb = ((size_t)bh * 32 + kt) * 4096;

        #pragma unroll
        for (int p = 0; p < 2; ++p) {
            if (part == 2) {
                #pragma unroll
                for (int jj = 0; jj < 2; ++jj) {
                    const int j = 2 * p + jj;
                    #pragma unroll
                    for (int i = 0; i < 4; ++i) {
                        bf16x4 v4;
                        #pragma unroll
                        for (int r = 0; r < 4; ++r)
                            v4[r] = (__bf16)(acc[4 * mi + i][j][r] + bv[j]);
                        *reinterpret_cast<bf16x4*>(
                            &scrH[(jj * 16 + n16) * 72 + i * 16 + quad * 4]) = v4;
                    }
                }
            } else {
                #pragma unroll
                for (int ii = 0; ii < 2; ++ii) {
                    const int i = 2 * p + ii;
                    #pragma unroll
                    for (int j = 0; j < 4; ++j) {
                        #pragma unroll
                        for (int r = 0; r < 4; ++r) {
                            float val = acc[4 * mi + i][j][r] + bv[j];
                            if (part == 0) val *= QSCALE;   // 1/sqrt(HD)*log2e
                            __bf16 h = (__bf16)val;
                            const int so = (ii * 16 + quad * 4 + r) * 72 + j * 16 + n16;
                            scrH[so] = h;
                            scrL[so] = (__bf16)(val - (float)h);
                        }
                    }
                }
            }
            __syncthreads();

            if (part == 0) {
                const size_t qbase = ((size_t)bh * SEQ + s0 + 32 * p + lr) * 128;
                #pragma unroll
                for (int t = 0; t < 4; ++t) {
                    const int ch = hc * 4 + t;
                    *reinterpret_cast<bf16x8*>(&qs[qbase + ch * 8]) =
                        *reinterpret_cast<const bf16x8*>(&scrH[lr * 72 + ch * 8]);
                    *reinterpret_cast<bf16x8*>(&qs[qbase + 64 + ch * 8]) =
                        *reinterpret_cast<const bf16x8*>(&scrL[lr * 72 + ch * 8]);
                }
            } else if (part == 1) {
                const int kr = 32 * p + lr;
                #pragma unroll
                for (int t = 0; t < 4; ++t) {
                    const int ch = hc * 4 + t;
                    const int src = (ch ^ (lr & 7)) * 8;
                    *reinterpret_cast<bf16x8*>(&khi_g[tb + kr * 64 + ch * 8]) =
                        *reinterpret_cast<const bf16x8*>(&scrH[lr * 72 + src]);
                    *reinterpret_cast<bf16x8*>(&klo_g[tb + kr * 64 + ch * 8]) =
                        *reinterpret_cast<const bf16x8*>(&scrL[lr * 72 + src]);
                }
            } else {
                const int d = 32 * p + lr;
                #pragma unroll
                for (int t = 0; t < 4; ++t) {
                    const int ch = hc * 4 + t;
                    const int src = (ch ^ (lr & 7)) * 8;
                    *reinterpret_cast<bf16x8*>(&vt_g[tb + d * 64 + ch * 8]) =
                        *reinterpret_cast<const bf16x8*>(&scrH[lr * 72 + src]);
                }
            }
            __syncthreads();
        }
    }
}

// ---------------- out-proj GEMM (bf16x3, 128x64 tile, fused-K loop) ----------
__launch_bounds__(256)
__global__ void gemm_out_kernel(const __bf16* __restrict__ A,
                                const __bf16* __restrict__ Bt,
                                const float* __restrict__ bias,
                                float* __restrict__ out)
{
    __shared__ __align__(16) __bf16 AsH[128 * 32];
    __shared__ __align__(16) __bf16 AsL[128 * 32];
    __shared__ __align__(16) __bf16 BsH[64 * 32];
    __shared__ __align__(16) __bf16 BsL[64 * 32];

    const int tid  = threadIdx.x;
    const int w    = tid >> 6;
    const int lane = tid & 63;
    const int n16  = lane & 15;
    const int quad = lane >> 4;
    const int bm = blockIdx.x * 128, bn = blockIdx.y * 64;
    const int wm = (w & 1) * 64,     wn = (w >> 1) * 32;

    const int srow = tid >> 2, sc = (tid & 3) * 8;
    const __bf16* Ar = A  + (size_t)(bm + srow) * (2*DM) + sc;
    const __bf16* Br = Bt + (size_t)(bn + srow) * (2*DM) + sc;   // rows 0..63

    f32x4 acc[4][2] = {};

    for (int k0 = 0; k0 < DM; k0 += 32) {
        __syncthreads();
        gld_lds16(Ar + k0,                         &AsH[(size_t)tid * 8]);
        gld_lds16(Ar + k0 + (size_t)64*2*DM,       &AsH[(size_t)(256 + tid) * 8]);
        gld_lds16(Ar + DM + k0,                    &AsL[(size_t)tid * 8]);
        gld_lds16(Ar + DM + k0 + (size_t)64*2*DM,  &AsL[(size_t)(256 + tid) * 8]);
        gld_lds16(Br + k0,                         &BsH[(size_t)tid * 8]);
        gld_lds16(Br + DM + k0,                    &BsL[(size_t)tid * 8]);
        __syncthreads();

        bf16x8 afh[4], afl[4], bfh[2], bfl[2];
        #pragma unroll
        for (int i = 0; i < 4; ++i) {
            const int ro = (wm + i*16 + n16) * 32 + quad * 8;
            afh[i] = *reinterpret_cast<const bf16x8*>(&AsH[ro]);
            afl[i] = *reinterpret_cast<const bf16x8*>(&AsL[ro]);
        }
        #pragma unroll
        for (int j = 0; j < 2; ++j) {
            const int ro = (wn + j*16 + n16) * 32 + quad * 8;
            bfh[j] = *reinterpret_cast<const bf16x8*>(&BsH[ro]);
            bfl[j] = *reinterpret_cast<const bf16x8*>(&BsL[ro]);
        }
        #pragma unroll
        for (int i = 0; i < 4; ++i)
            #pragma unroll
            for (int j = 0; j < 2; ++j) {
                acc[i][j] = __builtin_amdgcn_mfma_f32_16x16x32_bf16(afh[i], bfh[j], acc[i][j], 0, 0, 0);
                acc[i][j] = __builtin_amdgcn_mfma_f32_16x16x32_bf16(afh[i], bfl[j], acc[i][j], 0, 0, 0);
                acc[i][j] = __builtin_amdgcn_mfma_f32_16x16x32_bf16(afl[i], bfh[j], acc[i][j], 0, 0, 0);
            }
    }

    #pragma unroll
    for (int j = 0; j < 2; ++j) {
        const int col = bn + wn + j * 16 + n16;
        const float bvv = bias[col];
        #pragma unroll
        for (int i = 0; i < 4; ++i) {
            const int row0 = bm + wm + i * 16 + quad * 4;
            #pragma unroll
            for (int r = 0; r < 4; ++r)
                out[(size_t)(row0 + r) * DM + col] = acc[i][j][r] + bvv;
        }
    }
}

// ---------------- Flash attention: 8 waves x 16 q-rows, G=2 staging --------
// grid 512 (XCD-swizzled), 512 threads. Wave w owns queries qt*128 + w*16..+15.
// Two 24KB K/V tiles staged per barrier pair (6 chunks/wave over 8 waves);
// 64KB LDS -> 2 blocks/CU co-resident -> 16 waves/CU = 4 waves/SIMD.
__launch_bounds__(512, 2)
__global__ void flash_attn_v6_kernel(const __bf16* __restrict__ qs,
                                     const __bf16* __restrict__ khi_g,
                                     const __bf16* __restrict__ klo_g,
                                     const __bf16* __restrict__ vt_g,
                                     __bf16* __restrict__ ctx2)
{
    __shared__ __align__(16) __bf16 Khi[2][4096];
    __shared__ __align__(16) __bf16 Klo[2][4096];
    __shared__ __align__(16) __bf16 Vt [2][4096];
    __shared__ __align__(16) __bf16 Ps [8192];   // 128 q-rows x 64, swizzled

    const int tid  = threadIdx.x;
    const int w    = tid >> 6;            // 0..7
    const int lane = tid & 63;
    const int n16  = lane & 15;
    const int quad = lane >> 4;
    const int bid  = blockIdx.x;
    const int bh = (bid & 7) * 4 + (bid >> 7);
    const int qt = (bid >> 3) & 15;

    bf16x8 qh[2], ql[2];
    {
        const size_t qrow =
            ((size_t)bh * SEQ + qt * 128 + w * 16 + n16) * 128;
        #pragma unroll
        for (int s2 = 0; s2 < 2; ++s2) {
            qh[s2] = *reinterpret_cast<const bf16x8*>(&qs[qrow + s2 * 32 + quad * 8]);
            ql[s2] = *reinterpret_cast<const bf16x8*>(&qs[qrow + 64 + s2 * 32 + quad * 8]);
        }
    }

    f32x4 o[4] = {};
    float l_lane = 0.f;

    for (int kt2 = 0; kt2 < 16; ++kt2) {
        __syncthreads();
        // 48 x 1KB chunks over 8 waves: waves 0-3 -> buffer 0 (tile 2*kt2),
        // waves 4-7 -> buffer 1 (tile 2*kt2+1). 6 chunks per wave.
        {
            const int buf = w >> 2;
            const size_t tb = ((size_t)bh * 32 + kt2 * 2 + buf) * 4096;
            #pragma unroll
            for (int t = 0; t < 6; ++t) {
                const int rem = (w & 3) * 6 + t;     // 0..23
                const int arr = rem >> 3, sub = rem & 7;
                const int eo = sub * 512 + lane * 8;
                const __bf16* g = (arr == 0 ? khi_g : arr == 1 ? klo_g : vt_g) + tb + eo;
                __bf16* l = (arr == 0 ? Khi[buf] : arr == 1 ? Klo[buf] : Vt[buf]) + eo;
                gld_lds16(g, l);
            }
        }
        __syncthreads();

        #pragma unroll
        for (int hf = 0; hf < 2; ++hf) {
            const __bf16* KhiB = Khi[hf];
            const __bf16* KloB = Klo[hf];
            const __bf16* VtB  = Vt[hf];

            #pragma unroll
            for (int kg = 0; kg < 4; ++kg) {
                const int r = kg * 16 + n16;
                const int o0 = r * 64 + ((quad ^ (r & 7)) << 3);
                const int o1 = r * 64 + (((4 + quad) ^ (r & 7)) << 3);
                bf16x8 kh0 = *reinterpret_cast<const bf16x8*>(&KhiB[o0]);
                bf16x8 kl0 = *reinterpret_cast<const bf16x8*>(&KloB[o0]);
                bf16x8 kh1 = *reinterpret_cast<const bf16x8*>(&KhiB[o1]);
                bf16x8 kl1 = *reinterpret_cast<const bf16x8*>(&KloB[o1]);

                // two independent 3-deep chains, then one add
                f32x4 sa = {}, sb = {};
                sa = __builtin_amdgcn_mfma_f32_16x16x32_bf16(kh0, qh[0], sa, 0, 0, 0);
                sb = __builtin_amdgcn_mfma_f32_16x16x32_bf16(kh1, qh[1], sb, 0, 0, 0);
                sa = __builtin_amdgcn_mfma_f32_16x16x32_bf16(kl0, qh[0], sa, 0, 0, 0);
                sb = __builtin_amdgcn_mfma_f32_16x16x32_bf16(kl1, qh[1], sb, 0, 0, 0);
                sa = __builtin_amdgcn_mfma_f32_16x16x32_bf16(kh0, ql[0], sa, 0, 0, 0);
                sb = __builtin_amdgcn_mfma_f32_16x16x32_bf16(kh1, ql[1], sb, 0, 0, 0);
                f32x4 st = sa + sb;

                f32x4 pp;
                #pragma unroll
                for (int r2 = 0; r2 < 4; ++r2) pp[r2] = exp2f(st[r2]);
                l_lane += (pp[0] + pp[1]) + (pp[2] + pp[3]);

                bf16x4 p4;
                #pragma unroll
                for (int r2 = 0; r2 < 4; ++r2) p4[r2] = (__bf16)pp[r2];
                const int prow = w * 16 + n16;
                const int ch2 = kg * 2 + (quad >> 1);
                const int off = prow * 64 + ((ch2 ^ (prow & 7)) << 3) + (quad & 1) * 4;
                *reinterpret_cast<bf16x4*>(&Ps[off]) = p4;
            }

            bf16x8 pa[2];
            {
                const int prow = w * 16 + n16;
                #pragma unroll
                for (int s2 = 0; s2 < 2; ++s2)
                    pa[s2] = *reinterpret_cast<const bf16x8*>(
                        &Ps[prow * 64 + (((s2 * 4 + quad) ^ (prow & 7)) << 3)]);
            }
            #pragma unroll
            for (int c = 0; c < 4; ++c) {
                const int vr = c * 16 + n16;
                bf16x8 vb0 = *reinterpret_cast<const bf16x8*>(
                    &VtB[vr * 64 + ((quad ^ (vr & 7)) << 3)]);
                bf16x8 vb1 = *reinterpret_cast<const bf16x8*>(
                    &VtB[vr * 64 + (((4 + quad) ^ (vr & 7)) << 3)]);
                o[c] = __builtin_amdgcn_mfma_f32_16x16x32_bf16(pa[0], vb0, o[c], 0, 0, 0);
                o[c] = __builtin_amdgcn_mfma_f32_16x16x32_bf16(pa[1], vb1, o[c], 0, 0, 0);
            }
        }
    }

    l_lane += __shfl_xor(l_lane, 16, 64);
    l_lane += __shfl_xor(l_lane, 32, 64);

    const int b = bh >> 4, hh = bh & 15;
    #pragma unroll
    for (int r2 = 0; r2 < 4; ++r2) {
        const float l = __shfl(l_lane, (quad << 4) + quad * 4 + r2, 64);
        const float linv = 1.0f / l;
        const int srow = qt * 128 + w * 16 + quad * 4 + r2;
        const size_t rowoff = (size_t)(b * SEQ + srow) * (2*DM);
        #pragma unroll
        for (int c = 0; c < 4; ++c) {
            const int col = hh * HD + c * 16 + n16;
            float v = o[c][r2] * linv;
            __bf16 h = (__bf16)v;
            ctx2[rowoff + col] = h;
            ctx2[rowoff + DM + col] = (__bf16)(v - (float)h);
        }
    }
}

extern "C" void kernel_launch(void* const* d_in, const int* in_sizes, int n_in,
                              void* d_out, int out_size, void* d_ws, size_t ws_size,
                              hipStream_t stream)
{
    const float* x    = (const float*)d_in[0];
    const float* Wqkv = (const float*)d_in[1];
    const float* bqkv = (const float*)d_in[2];
    const float* Wout = (const float*)d_in[3];
    const float* bout = (const float*)d_in[4];
    float* out = (float*)d_out;

    // ws layout (MB): 0-16 xs (alias ctx2) | 16-28 wqt | 28-32 wot |
    //                 32-48 qs | 48-56 khi | 56-64 klo | 64-72 vt
    char* ws = (char*)d_ws;
    __bf16* xs   = (__bf16*)(ws);
    __bf16* ctx2 = xs;
    __bf16* wqt  = (__bf16*)(ws + (size_t)16 * 1024 * 1024);
    __bf16* wot  = (__bf16*)(ws + (size_t)28 * 1024 * 1024);
    __bf16* qsb  = (__bf16*)(ws + (size_t)32 * 1024 * 1024);
    __bf16* khi  = (__bf16*)(ws + (size_t)48 * 1024 * 1024);
    __bf16* klo  = (__bf16*)(ws + (size_t)56 * 1024 * 1024);
    __bf16* vt   = (__bf16*)(ws + (size_t)64 * 1024 * 1024);

    prep_kernel<<<dim3(5120), 256, 0, stream>>>(x, Wqkv, Wout, xs, wqt, wot);
    gemm_qkv_kernel<<<dim3(192), 512, 0, stream>>>(
        xs, wqt, bqkv, qsb, khi, klo, vt);
    flash_attn_v6_kernel<<<dim3(512), 512, 0, stream>>>(qsb, khi, klo, vt, ctx2);
    gemm_out_kernel<<<dim3(M_TOT / 128, DM / 64), 256, 0, stream>>>(
        ctx2, wot, bout, out);
}